// Round 1
// baseline (674.261 us; speedup 1.0000x reference)
//
#include <hip/hip_runtime.h>

// KMeans assignment step: costs[i] = min_k ||x_i - c_k||^2, indices[i] = argmin_k.
// d2 = x2 + c2 - 2*x.c ; clamp >= 0 ; min/argmin over k (first-occurrence ties).
//
// N=131072 points, D=128 dims, K=1024 centers, fp32.
// Output: d_out = [costs (N floats), indices-as-float (N floats)].

constexpr int N  = 131072;
constexpr int D  = 128;
constexpr int K  = 1024;

constexpr int MT = 64;    // points per block
constexpr int KT = 128;   // centers per tile (8 tiles over K)
constexpr int DT = 32;    // d chunk for C staging
constexpr int XS = 65;    // X_lds stride over m (padded)
constexpr int CS = 129;   // C_lds stride over c (padded)

// ---- kernel 1: center norms c2[k] = sum_d centers[k][d]^2 ----
__global__ void c2_kernel(const float* __restrict__ centers, float* __restrict__ c2) {
    const int b = blockIdx.x;       // center index 0..K-1
    const int lane = threadIdx.x;   // 0..63
    const float* row = centers + (size_t)b * D;
    float v0 = row[lane], v1 = row[lane + 64];
    float s = v0 * v0 + v1 * v1;
    #pragma unroll
    for (int off = 32; off > 0; off >>= 1)
        s += __shfl_down(s, off, 64);
    if (lane == 0) c2[b] = s;
}

// ---- kernel 2: tiled distance + min/argmin ----
__global__ __launch_bounds__(256, 2) void kmeans_fp32(
    const float* __restrict__ x, const float* __restrict__ centers,
    const float* __restrict__ c2, float* __restrict__ out_cost,
    float* __restrict__ out_idx)
{
    __shared__ float Xl[D * XS];      // [dd][m]   33280 B
    __shared__ float Cl[DT * CS];     // [dd][c]   16512 B
    __shared__ float c2l[K];          //            4096 B
    __shared__ float x2l[MT];         //             256 B
    __shared__ float redV[MT * 16];   //            4096 B
    __shared__ int   redI[MT * 16];   //            4096 B
    // total ~61.5 KiB -> 2 blocks/CU

    const int tid = threadIdx.x;
    const int tx = tid & 15;          // center group
    const int ty = tid >> 4;          // point group
    const int m0 = blockIdx.x * MT;

    // ---- stage X tile (64 x 128) transposed into LDS [d][m] ----
    {
        const int d4 = (tid & 31) * 4;   // d offset (float4)
        const int mb = tid >> 5;         // 0..7
        #pragma unroll
        for (int p = 0; p < 8; ++p) {
            const int m = mb + p * 8;
            const float4 v = *(const float4*)(x + (size_t)(m0 + m) * D + d4);
            Xl[(d4 + 0) * XS + m] = v.x;
            Xl[(d4 + 1) * XS + m] = v.y;
            Xl[(d4 + 2) * XS + m] = v.z;
            Xl[(d4 + 3) * XS + m] = v.w;
        }
    }
    // ---- stage c2 (all 1024) ----
    for (int i = tid; i < K; i += 256) c2l[i] = c2[i];
    __syncthreads();

    // ---- x2 per point from LDS (exact fp32) ----
    if (tid < MT) {
        float s = 0.f;
        #pragma unroll 8
        for (int dd = 0; dd < D; ++dd) {
            const float v = Xl[dd * XS + tid];
            s += v * v;
        }
        x2l[tid] = s;
    }

    float bestV[4];
    int   bestI[4];
    #pragma unroll
    for (int i = 0; i < 4; ++i) { bestV[i] = 1e30f; bestI[i] = 0; }

    for (int ct = 0; ct < K / KT; ++ct) {
        float acc[4][8];
        #pragma unroll
        for (int i = 0; i < 4; ++i)
            #pragma unroll
            for (int j = 0; j < 8; ++j) acc[i][j] = 0.f;

        for (int dc = 0; dc < D / DT; ++dc) {
            __syncthreads();  // protect Cl from previous use
            // stage C chunk (128 centers x 32 d) transposed into LDS [d][c]
            {
                const int d4 = (tid & 7) * 4;   // 0..28
                const int cb = tid >> 3;        // 0..31
                #pragma unroll
                for (int p = 0; p < 4; ++p) {
                    const int c = cb + p * 32;
                    const float4 v = *(const float4*)(centers +
                        (size_t)(ct * KT + c) * D + dc * DT + d4);
                    Cl[(d4 + 0) * CS + c] = v.x;
                    Cl[(d4 + 1) * CS + c] = v.y;
                    Cl[(d4 + 2) * CS + c] = v.z;
                    Cl[(d4 + 3) * CS + c] = v.w;
                }
            }
            __syncthreads();

            #pragma unroll
            for (int dd = 0; dd < DT; ++dd) {
                const float4 xa  = *(const float4*)&Xl[(dc * DT + dd) * XS + 4 * ty];
                const float4 ca  = *(const float4*)&Cl[dd * CS + 4 * tx];
                const float4 cb4 = *(const float4*)&Cl[dd * CS + 64 + 4 * tx];
                const float xs[4] = {xa.x, xa.y, xa.z, xa.w};
                const float cs[8] = {ca.x, ca.y, ca.z, ca.w, cb4.x, cb4.y, cb4.z, cb4.w};
                #pragma unroll
                for (int i = 0; i < 4; ++i)
                    #pragma unroll
                    for (int j = 0; j < 8; ++j)
                        acc[i][j] += xs[i] * cs[j];
            }
        }

        // ---- epilogue for this center tile: s = c2 - 2*dot, running min ----
        #pragma unroll
        for (int j = 0; j < 8; ++j) {
            const int cl = (j < 4) ? (4 * tx + j) : (64 + 4 * tx + (j - 4));
            const int gidx = ct * KT + cl;
            const float cc = c2l[ct * KT + cl];
            #pragma unroll
            for (int i = 0; i < 4; ++i) {
                const float s = cc - 2.f * acc[i][j];
                // first-occurrence tie-break like jnp.argmin
                if (s < bestV[i] || (s == bestV[i] && gidx < bestI[i])) {
                    bestV[i] = s;
                    bestI[i] = gidx;
                }
            }
        }
    }

    // ---- cross-thread (tx) reduction per point ----
    #pragma unroll
    for (int i = 0; i < 4; ++i) {
        const int m = 4 * ty + i;
        redV[m * 16 + tx] = bestV[i];
        redI[m * 16 + tx] = bestI[i];
    }
    __syncthreads();
    if (tid < MT) {
        float bv = redV[tid * 16 + 0];
        int   bi = redI[tid * 16 + 0];
        #pragma unroll
        for (int t = 1; t < 16; ++t) {
            const float v = redV[tid * 16 + t];
            const int  ii = redI[tid * 16 + t];
            if (v < bv || (v == bv && ii < bi)) { bv = v; bi = ii; }
        }
        float cost = x2l[tid] + bv;   // d2 = x2 + (c2 - 2 dot)
        if (cost < 0.f) cost = 0.f;   // clamp like reference
        out_cost[m0 + tid] = cost;
        out_idx[m0 + tid]  = (float)bi;
    }
}

extern "C" void kernel_launch(void* const* d_in, const int* in_sizes, int n_in,
                              void* d_out, int out_size, void* d_ws, size_t ws_size,
                              hipStream_t stream) {
    const float* x       = (const float*)d_in[0];
    const float* centers = (const float*)d_in[1];
    float* c2       = (float*)d_ws;          // 1024 floats scratch
    float* out_cost = (float*)d_out;         // [N]
    float* out_idx  = out_cost + N;          // [N] indices stored as float

    c2_kernel<<<K, 64, 0, stream>>>(centers, c2);
    kmeans_fp32<<<N / MT, 256, 0, stream>>>(x, centers, c2, out_cost, out_idx);
}

// Round 2
// 183.108 us; speedup vs baseline: 3.6823x; 3.6823x over previous
//
#include <hip/hip_runtime.h>

// KMeans assignment: costs[i] = min_k ||x_i-c_k||^2, indices[i] = argmin_k.
// argmin over k of d2 = argmin of (c2[k] - 2*dot(x,c_k))  (x2 is additive).
// Cross term via split-f16 3-pass MFMA: x = xh + xl, c = ch + cl,
//   dot ~= xh.ch + xl.ch + xh.cl   (error ~1e-5, below fp32-chain noise).
// x2, c2 exact fp32.  N=131072, D=128, K=1024.
// d_out = [costs (N f32), indices-as-f32 (N)].

typedef _Float16 f16x8 __attribute__((ext_vector_type(8)));
typedef float    f32x4 __attribute__((ext_vector_type(4)));
typedef unsigned short u16;

constexpr int N = 131072, D = 128, K = 1024;
constexpr int MT = 128;   // points per block

union H2U { _Float16 h; unsigned short u; };

__device__ inline void gl_lds16(const void* g, void* l) {
  __builtin_amdgcn_global_load_lds(
      (const __attribute__((address_space(1))) unsigned int*)g,
      (__attribute__((address_space(3))) unsigned int*)l, 16, 0, 0);
}

// ---- prep: centers -> hi/lo f16 in fragment-major tiled layout + exact c2 ----
// layout (ushort idx): (((cb*4 + kc)*4 + q)*128 + c%128)*8 + j
//   where k = kc*32 + q*8 + j  (matches MFMA A/B frag: lane=q*16+ln reads 16B)
__global__ void prep_centers(const float* __restrict__ centers,
                             u16* __restrict__ Bh, u16* __restrict__ Bl,
                             float* __restrict__ c2) {
  const int wave = threadIdx.x >> 6, lane = threadIdx.x & 63;
  const int c = blockIdx.x * 4 + wave;          // 0..1023, one wave per center
  const float2 v = ((const float2*)(centers + (size_t)c * D))[lane]; // k=2l,2l+1
  float s = v.x * v.x + v.y * v.y;
  #pragma unroll
  for (int off = 32; off; off >>= 1) s += __shfl_xor(s, off, 64);
  if (lane == 0) c2[c] = s;

  H2U h0, h1, l0, l1;
  h0.h = (_Float16)v.x;  l0.h = (_Float16)(v.x - (float)h0.h);
  h1.h = (_Float16)v.y;  l1.h = (_Float16)(v.y - (float)h1.h);
  const int cb = c >> 7, cm = c & 127;
  const int kc = lane >> 4, q = (lane >> 2) & 3, j0 = (lane & 3) * 2;
  const size_t off = (((size_t)(cb * 4 + kc) * 4 + q) * 128 + cm) * 8 + j0;
  *(unsigned*)(Bh + off) = (unsigned)h0.u | ((unsigned)h1.u << 16);
  *(unsigned*)(Bl + off) = (unsigned)l0.u | ((unsigned)l1.u << 16);
}

// ---- main: 128 pts x 1024 centers per block; wave tile 64x64 ----
__global__ __launch_bounds__(256, 2) void kmeans_mfma(
    const float* __restrict__ x,
    const u16* __restrict__ Bh_g, const u16* __restrict__ Bl_g,
    const float* __restrict__ c2g,
    float* __restrict__ out_cost, float* __restrict__ out_idx)
{
  // 80 KB exactly -> 2 blocks/CU
  __shared__ __align__(16) u16 Ah[16384];   // [kc4][q4][m128][j8]  32 KB
  __shared__ __align__(16) u16 Al[16384];   //                      32 KB
  __shared__ __align__(16) u16 Bbuf[8192];  // Bh[0:4096] Bl[4096:] 16 KB (reused for final reduce)

  const int tid = threadIdx.x;
  const int wave = tid >> 6, lane = tid & 63;
  const int wr = wave >> 1, wc = wave & 1;    // wave row/col in 2x2
  const int q = lane >> 4, ln = lane & 15;
  const int m0 = blockIdx.x * MT;

  // ---- stage A tile: fp32 -> (hi,lo) f16, tiled layout, once per block ----
  #pragma unroll
  for (int i = 0; i < 16; ++i) {
    const int flat = i * 256 + tid;            // 4096 float4s = 128x128 floats
    const int m = flat >> 5, c4 = flat & 31, k0 = c4 * 4;
    const float4 v = *(const float4*)(x + (size_t)(m0 + m) * D + k0);
    const int kc = k0 >> 5, qq = (k0 >> 3) & 3, j0 = k0 & 7;
    const float vv[4] = {v.x, v.y, v.z, v.w};
    H2U h[4], l[4];
    #pragma unroll
    for (int z = 0; z < 4; ++z) {
      h[z].h = (_Float16)vv[z];
      l[z].h = (_Float16)(vv[z] - (float)h[z].h);
    }
    const int off = ((kc * 4 + qq) * 128 + m) * 8 + j0;
    uint2 hp, lp;
    hp.x = h[0].u | ((unsigned)h[1].u << 16); hp.y = h[2].u | ((unsigned)h[3].u << 16);
    lp.x = l[0].u | ((unsigned)l[1].u << 16); lp.y = l[2].u | ((unsigned)l[3].u << 16);
    *(uint2*)(Ah + off) = hp;
    *(uint2*)(Al + off) = lp;
  }
  __syncthreads();

  // ---- x2 per point (thread tid<128 owns m=tid; stays in a register) ----
  float x2m = 0.f;
  if (tid < MT) {
    #pragma unroll
    for (int kq = 0; kq < 16; ++kq) {
      const f16x8 hv = *(const f16x8*)(Ah + (kq * 128 + tid) * 8);
      const f16x8 lv = *(const f16x8*)(Al + (kq * 128 + tid) * 8);
      #pragma unroll
      for (int e = 0; e < 8; ++e) {
        const float xv = (float)hv[e] + (float)lv[e];
        x2m += xv * xv;
      }
    }
  }

  float bestV[16]; int bestI[16];
  #pragma unroll
  for (int b = 0; b < 16; ++b) { bestV[b] = 3.4e38f; bestI[b] = 0; }

  for (int ct = 0; ct < 8; ++ct) {
    f32x4 acc[4][4];
    #pragma unroll
    for (int mt = 0; mt < 4; ++mt)
      #pragma unroll
      for (int nt = 0; nt < 4; ++nt)
        acc[mt][nt] = (f32x4){0.f, 0.f, 0.f, 0.f};

    for (int kc = 0; kc < 4; ++kc) {
      __syncthreads();                         // prev frag reads done
      { // stage B chunk (8 KB hi + 8 KB lo), contiguous stream
        const size_t gbase = (size_t)(ct * 4 + kc) * 4096;   // ushort units
        #pragma unroll
        for (int i = 0; i < 2; ++i) {
          const size_t eoff = (size_t)i * 2048 + (size_t)wave * 512; // wave-uniform
          gl_lds16(Bh_g + gbase + eoff + (size_t)lane * 8, Bbuf + eoff);
          gl_lds16(Bl_g + gbase + eoff + (size_t)lane * 8, Bbuf + 4096 + eoff);
        }
      }
      __syncthreads();                         // vmcnt(0) drain -> B ready

      f16x8 ah[4], al[4], bh[4], bl[4];
      #pragma unroll
      for (int t = 0; t < 4; ++t) {
        const int moff = ((kc * 4 + q) * 128 + wr * 64 + t * 16 + ln) * 8;
        ah[t] = *(const f16x8*)(Ah + moff);
        al[t] = *(const f16x8*)(Al + moff);
        const int noff = (q * 128 + wc * 64 + t * 16 + ln) * 8;
        bh[t] = *(const f16x8*)(Bbuf + noff);
        bl[t] = *(const f16x8*)(Bbuf + 4096 + noff);
      }
      // 3-pass split-f16: 48 MFMA per 16 ds_read_b128
      #pragma unroll
      for (int mt = 0; mt < 4; ++mt)
        #pragma unroll
        for (int nt = 0; nt < 4; ++nt)
          acc[mt][nt] = __builtin_amdgcn_mfma_f32_16x16x32_f16(ah[mt], bh[nt], acc[mt][nt], 0, 0, 0);
      #pragma unroll
      for (int mt = 0; mt < 4; ++mt)
        #pragma unroll
        for (int nt = 0; nt < 4; ++nt)
          acc[mt][nt] = __builtin_amdgcn_mfma_f32_16x16x32_f16(al[mt], bh[nt], acc[mt][nt], 0, 0, 0);
      #pragma unroll
      for (int mt = 0; mt < 4; ++mt)
        #pragma unroll
        for (int nt = 0; nt < 4; ++nt)
          acc[mt][nt] = __builtin_amdgcn_mfma_f32_16x16x32_f16(ah[mt], bl[nt], acc[mt][nt], 0, 0, 0);
    }

    // epilogue: s = c2 - 2*dot; running min (n strictly increasing per lane)
    #pragma unroll
    for (int nt = 0; nt < 4; ++nt) {
      const int n = ct * 128 + wc * 64 + nt * 16 + ln;
      const float c2v = c2g[n];
      #pragma unroll
      for (int mt = 0; mt < 4; ++mt)
        #pragma unroll
        for (int r = 0; r < 4; ++r) {
          const float s = __builtin_fmaf(-2.f, acc[mt][nt][r], c2v);
          const int b = mt * 4 + r;
          if (s < bestV[b]) { bestV[b] = s; bestI[b] = n; }
        }
    }
  }

  // ---- reduce across 16 lanes (ln) sharing the same m rows ----
  #pragma unroll
  for (int b = 0; b < 16; ++b) {
    float v = bestV[b]; int idx = bestI[b];
    #pragma unroll
    for (int off = 1; off < 16; off <<= 1) {
      const float ov = __shfl_xor(v, off, 64);
      const int   oi = __shfl_xor(idx, off, 64);
      if (ov < v || (ov == v && oi < idx)) { v = ov; idx = oi; }
    }
    bestV[b] = v; bestI[b] = idx;
  }

  __syncthreads();                 // done with B tiles; overlay reduce bufs
  float* redV = (float*)Bbuf;            // 256 floats (1 KB)
  int*   redI = (int*)(Bbuf + 4096);     // 256 ints   (at byte 8192)
  if (ln == 0) {
    #pragma unroll
    for (int b = 0; b < 16; ++b) {
      const int ml = wr * 64 + (b >> 2) * 16 + q * 4 + (b & 3);
      redV[ml * 2 + wc] = bestV[b];
      redI[ml * 2 + wc] = bestI[b];
    }
  }
  __syncthreads();
  if (tid < MT) {
    float v = redV[tid * 2]; int idx = redI[tid * 2];
    const float v1 = redV[tid * 2 + 1]; const int i1 = redI[tid * 2 + 1];
    if (v1 < v || (v1 == v && i1 < idx)) { v = v1; idx = i1; }
    float cost = x2m + v;
    if (cost < 0.f) cost = 0.f;          // clamp like reference
    out_cost[m0 + tid] = cost;
    out_idx[m0 + tid]  = (float)idx;
  }
}

extern "C" void kernel_launch(void* const* d_in, const int* in_sizes, int n_in,
                              void* d_out, int out_size, void* d_ws, size_t ws_size,
                              hipStream_t stream) {
  const float* x       = (const float*)d_in[0];
  const float* centers = (const float*)d_in[1];
  u16*   Bh = (u16*)d_ws;          // 256 KB
  u16*   Bl = Bh + (size_t)K * D;  // 256 KB
  float* c2 = (float*)(Bl + (size_t)K * D);  // 4 KB  (total ws use: 516 KB)
  float* out_cost = (float*)d_out;
  float* out_idx  = out_cost + N;

  prep_centers<<<K / 4, 256, 0, stream>>>(centers, Bh, Bl, c2);
  kmeans_mfma<<<N / MT, 256, 0, stream>>>(x, Bh, Bl, c2, out_cost, out_idx);
}